// Round 10
// baseline (285.403 us; speedup 1.0000x reference)
//
#include <hip/hip_runtime.h>

// ContextTokenModel — round 10: split parallel/serial work.
// K2a: embed + layer-0 x-projection (parallel, MFMA-dense) -> gxcx0
// K3a: layer-0 recurrence (thin serial chain: 6 MFMA/step)  -> y0a A-frags
// K2b: layer-1 x-projection from y0a (parallel)             -> gxcx1 (aliases gxcx0)
// K3b: layer-1 recurrence (6 MFMA/step), fp32 output [B,21,64]
// Output dtype fp32 (r7 beacon + r8 green proved it). Probes from r8.

typedef __attribute__((ext_vector_type(8))) short short8;
typedef __attribute__((ext_vector_type(8))) __bf16 bf16x8;
typedef __attribute__((ext_vector_type(4))) float f32x4;
typedef unsigned short ushort_t;

#define NMT 10752               // 21*512 M-tiles (16 rows each)
#define NMG 1344                // NMT/8 wave-jobs per dir in projection kernels

// ---- bf16 cvt region (ushort offsets from ws+64) ----
#define U_TOKEMB  0
#define U_TYPEMB  640000
#define U_HOLE    800000
#define U_GKFW0   800160
#define U_GBFW0   812448
#define U_CKFW0   812512
#define U_CBFW0   818656
#define U_GKBW0   818688
#define U_GBBW0   830976
#define U_CKBW0   831040
#define U_CBBW0   837184
#define U_GKFW1   837216
#define U_GBFW1   843360
#define U_CKFW1   843424
#define U_CBFW1   846496
#define U_GKBW1   846528
#define U_GBBW1   852672
#define U_CKBW1   852736
#define U_CBBW1   855808

#define MB_OFF    (2u << 20)              // mask bitmasks
#define GX_OFF    (4u << 20)              // gxcx0 / gxcx1 (aliased): 66,060,288 B
#define Y0A_OFF   (72u << 20)             // y0a A-frags: 22,020,096 B (ends 93 MiB)

__device__ __forceinline__ float bf2f(unsigned int u) {
  union { unsigned int i; float f; } v; v.i = u << 16; return v.f;
}
__device__ __forceinline__ unsigned short f2bf(float f) {
  unsigned int u = __float_as_uint(f);
  u += 0x7fffu + ((u >> 16) & 1u);
  return (unsigned short)(u >> 16);
}
__device__ __forceinline__ f32x4 mfma16(short8 a, short8 b, f32x4 c) {
  return __builtin_amdgcn_mfma_f32_16x16x32_bf16(
      __builtin_bit_cast(bf16x8, a), __builtin_bit_cast(bf16x8, b), c, 0, 0, 0);
}
__device__ __forceinline__ f32x4 unpk2(uint2 g) {
  f32x4 r;
  r[0] = bf2f(g.x & 0xffffu); r[1] = bf2f(g.x >> 16);
  r[2] = bf2f(g.y & 0xffffu); r[3] = bf2f(g.y >> 16);
  return r;
}
__device__ __forceinline__ float sgm(float x) {
  x = fminf(fmaxf(x, -30.f), 30.f);
  return 1.f / (1.f + __expf(-x));
}
__device__ __forceinline__ float tnh(float x) {
  x = fminf(fmaxf(x, -15.f), 15.f);
  float e = __expf(2.f * x);
  return (e - 1.f) / (e + 1.f);
}

// ---------------------------------------------------------------------------
__global__ void k0_detect(const ushort_t* __restrict__ probe_f,
                          const unsigned* __restrict__ probe_m,
                          const unsigned* __restrict__ probe_t,
                          int* __restrict__ flags) {
  const int lane = threadIdx.x;  // 64
  int cnt = 0;
#pragma unroll
  for (int i = 0; i < 4; ++i) {
    unsigned e = ((unsigned)probe_f[lane + i * 64] >> 7) & 0xffu;
    if (e == 0u || (e >= 112u && e <= 134u)) cnt++;
  }
#pragma unroll
  for (int off = 32; off > 0; off >>= 1) cnt += __shfl_down(cnt, off, 64);
  const unsigned v = probe_m[lane];
  const unsigned long long bytelike =
      __ballot((v > 1u) && (v != 0x3F800000u) && ((v & 0xFEFEFEFEu) == 0u));
  const unsigned tv = probe_t[lane];
  const unsigned long long tlooksTypes =
      __ballot(!(tv == 0u || tv == 1u || tv == 0x3F800000u));
  if (lane == 0) {
    flags[0] = (cnt < 205) ? 1 : 0;
    flags[1] = bytelike ? 1 : 0;
    flags[2] = tlooksTypes ? 0 : 1;
  }
}

struct Cvt19 { const void* src[19]; int len[19]; int dst[19]; };

__global__ void kcvt(Cvt19 a, ushort_t* __restrict__ cvt, const int* __restrict__ flags) {
  const int fp32 = flags[0];
  int gid = blockIdx.x * blockDim.x + threadIdx.x;
#pragma unroll 1
  for (int s = 0; s < 19; ++s) {
    if (gid < a.len[s]) {
      cvt[a.dst[s] + gid] = fp32 ? f2bf(((const float*)a.src[s])[gid])
                                 : ((const ushort_t*)a.src[s])[gid];
      return;
    }
    gid -= a.len[s];
  }
}

__global__ void kmask(const void* __restrict__ slot_tb, const void* __restrict__ slot_mb,
                      const void* __restrict__ slot_ta, const void* __restrict__ slot_ma,
                      ushort_t* __restrict__ mbits, const int* __restrict__ flags) {
  const int id = blockIdx.x * blockDim.x + threadIdx.x;
  if (id >= 163840) return;
  const int side = (id >= 81920) ? 1 : 0;
  const int idx = id - side * 81920;
  const int sw = flags[2];
  const void* src = side ? (sw ? slot_ta : slot_ma) : (sw ? slot_tb : slot_mb);
  unsigned bits = 0;
  if (flags[1] == 1) {
    const unsigned char* p = (const unsigned char*)src;
#pragma unroll
    for (int nt = 0; nt < 10; ++nt) bits |= (p[idx * 10 + nt] ? 1u : 0u) << nt;
  } else {
    const unsigned* p = (const unsigned*)src;
#pragma unroll
    for (int nt = 0; nt < 10; ++nt) bits |= (p[idx * 10 + nt] ? 1u : 0u) << nt;
  }
  mbits[side * 81920 + idx] = (ushort_t)bits;
}

// ---------------------------------------------------------------------------
// gatherX: A-frags for timestep t, rows btile*16+(lane&15). (r9-validated)
// ---------------------------------------------------------------------------
__device__ __forceinline__ void gatherX(
    int t, int btile, int nl, int q,
    const int* __restrict__ tok_b, const int* __restrict__ typ_b,
    const int* __restrict__ tok_a, const int* __restrict__ typ_a,
    const ushort_t* __restrict__ cvt, const ushort_t* __restrict__ mbits,
    short8 af[5]) {
  const int b = btile * 16 + nl;
  if (t == 10) {
#pragma unroll
    for (int kt = 0; kt < 5; ++kt)
      af[kt] = __builtin_bit_cast(short8,
          *reinterpret_cast<const uint4*>(cvt + U_HOLE + kt * 32 + q * 8));
    return;
  }
  const int ts = (t < 10) ? t : t - 11;
  const int side = (t < 10) ? 0 : 1;
  const int* tks = side ? tok_a : tok_b;
  const int* tys = side ? typ_a : typ_b;
  const int tok = tks[b * 10 + ts];
#pragma unroll
  for (int kt = 0; kt < 4; ++kt)
    af[kt] = __builtin_bit_cast(short8,
        *reinterpret_cast<const uint4*>(cvt + U_TOKEMB + (size_t)tok * 128 + kt * 32 + q * 8));
  const unsigned bm = (unsigned)mbits[side * 81920 + b * 10 + ts];
  float mx[8];
#pragma unroll
  for (int j = 0; j < 8; ++j) mx[j] = -1e30f;
  const int base = (b * 10 + ts) * 10;
  for (int nt = 0; nt < 10; ++nt) {
    const int ty = tys[base + nt];
    const float pen = ((bm >> nt) & 1u) ? 0.f : -1000.f;
    uint4 e = *reinterpret_cast<const uint4*>(cvt + U_TYPEMB + (size_t)ty * 32 + q * 8);
    const unsigned w[4] = {e.x, e.y, e.z, e.w};
#pragma unroll
    for (int j2 = 0; j2 < 4; ++j2) {
      mx[2 * j2]     = fmaxf(mx[2 * j2],     bf2f(w[j2] & 0xffffu) + pen);
      mx[2 * j2 + 1] = fmaxf(mx[2 * j2 + 1], bf2f(w[j2] >> 16) + pen);
    }
  }
  short8 v;
#pragma unroll
  for (int j = 0; j < 8; ++j) v[j] = (short)f2bf(mx[j]);
  af[4] = v;
}

// ---------------------------------------------------------------------------
// K2a: embed + layer-0 x-projection (both dirs). gxcx0 bf16 C-frags w/ bias:
// ((dir*NMT+mtile)*6+tn)*64+lane, tn 0..3 gates, 4..5 candidate.
// ---------------------------------------------------------------------------
__global__ __launch_bounds__(256, 2) void k2a(
    const int* __restrict__ tok_b, const void* __restrict__ slot_tb,
    const int* __restrict__ tok_a, const void* __restrict__ slot_ta,
    const void* __restrict__ slot_mb, const void* __restrict__ slot_ma,
    const ushort_t* __restrict__ cvt, const ushort_t* __restrict__ mbits,
    uint2* __restrict__ gxcx, const int* __restrict__ flags) {
  const int wave = (int)((blockIdx.x * blockDim.x + threadIdx.x) >> 6);
  const int lane = threadIdx.x & 63;
  const int q = lane >> 4, nl = lane & 15;
  const int dir = wave & 1;
  const int mg = wave >> 1;
  if (mg >= NMG) return;
  const int sw = flags[2];
  const int* typ_b = (const int*)(sw ? slot_mb : slot_tb);
  const int* typ_a = (const int*)(sw ? slot_ma : slot_ta);

  const ushort_t* gk = cvt + (dir ? U_GKBW0 : U_GKFW0);
  const ushort_t* ck = cvt + (dir ? U_CKBW0 : U_CKFW0);
  const ushort_t* gb = cvt + (dir ? U_GBBW0 : U_GBFW0);
  const ushort_t* cb = cvt + (dir ? U_CBBW0 : U_CBFW0);

  short8 wf[5][6];
#pragma unroll
  for (int kt = 0; kt < 5; ++kt) {
#pragma unroll
    for (int tn = 0; tn < 6; ++tn) {
      const ushort_t* src = (tn < 4) ? gk : ck;
      const int ncol = (tn < 4) ? 64 : 32;
      const int n = (tn < 4) ? tn * 16 + nl : (tn - 4) * 16 + nl;
      short8 v;
#pragma unroll
      for (int j = 0; j < 8; ++j)
        v[j] = (short)src[(kt * 32 + q * 8 + j) * ncol + n];
      wf[kt][tn] = v;
    }
  }
  float bias[6];
#pragma unroll
  for (int tn = 0; tn < 6; ++tn)
    bias[tn] = bf2f((tn < 4) ? (unsigned)gb[tn * 16 + nl]
                             : (unsigned)cb[(tn - 4) * 16 + nl]);

  for (int mi = 0; mi < 8; ++mi) {
    const int mtile = mg * 8 + mi;
    const int t = mtile >> 9;
    const int btile = mtile & 511;
    short8 af[5];
    gatherX(t, btile, nl, q, tok_b, typ_b, tok_a, typ_a, cvt, mbits, af);
#pragma unroll
    for (int tn = 0; tn < 6; ++tn) {
      f32x4 acc = {bias[tn], bias[tn], bias[tn], bias[tn]};
#pragma unroll
      for (int kt = 0; kt < 5; ++kt) acc = mfma16(af[kt], wf[kt][tn], acc);
      uint2 o;
      o.x = (unsigned)f2bf(acc[0]) | ((unsigned)f2bf(acc[1]) << 16);
      o.y = (unsigned)f2bf(acc[2]) | ((unsigned)f2bf(acc[3]) << 16);
      gxcx[(((size_t)dir * NMT + mtile) * 6 + tn) * 64 + lane] = o;
    }
  }
}

// ---------------------------------------------------------------------------
// K3a: layer-0 recurrence (r3-validated). 6 MFMA/step. Writes y0a A-frags.
// ---------------------------------------------------------------------------
__global__ __launch_bounds__(256) void k3a(
    const ushort_t* __restrict__ cvt, const uint2* __restrict__ gxcx,
    uint4* __restrict__ y0a) {
  __shared__ __align__(16) ushort_t hbuf[4][2][16 * 40];
  const int wv = threadIdx.x >> 6;
  const int lane = threadIdx.x & 63;
  const int q = lane >> 4, nl = lane & 15;
  const int job = blockIdx.x * 4 + wv;
  const int dir = job & 1, btile = job >> 1;
  const ushort_t* gk = cvt + (dir ? U_GKBW0 : U_GKFW0);
  const ushort_t* ck = cvt + (dir ? U_CKBW0 : U_CKFW0);

  short8 wg[4], wc[2];
#pragma unroll
  for (int tn = 0; tn < 4; ++tn) {
    short8 v;
#pragma unroll
    for (int j = 0; j < 8; ++j) v[j] = (short)gk[(160 + q * 8 + j) * 64 + tn * 16 + nl];
    wg[tn] = v;
  }
#pragma unroll
  for (int tn = 0; tn < 2; ++tn) {
    short8 v;
#pragma unroll
    for (int j = 0; j < 8; ++j) v[j] = (short)ck[(160 + q * 8 + j) * 32 + tn * 16 + nl];
    wc[tn] = v;
  }

  f32x4 hc0 = {0.f, 0.f, 0.f, 0.f}, hc1 = {0.f, 0.f, 0.f, 0.f};
  short8 hA = {0, 0, 0, 0, 0, 0, 0, 0};
  ushort_t* hb0 = hbuf[wv][0];
  ushort_t* hb1 = hbuf[wv][1];

  const size_t dbase = (size_t)dir * NMT;
  uint2 gc[6], gn[6];
  {
    const int t0 = dir ? 20 : 0;
#pragma unroll
    for (int tn = 0; tn < 6; ++tn)
      gc[tn] = gxcx[((dbase + (size_t)(t0 * 512 + btile)) * 6 + tn) * 64 + lane];
  }

  for (int s = 0; s < 21; ++s) {
    const int t = dir ? 20 - s : s;
    if (s < 20) {
      const int t2 = dir ? t - 1 : t + 1;
#pragma unroll
      for (int tn = 0; tn < 6; ++tn)
        gn[tn] = gxcx[((dbase + (size_t)(t2 * 512 + btile)) * 6 + tn) * 64 + lane];
    }

    f32x4 ru[4];
#pragma unroll
    for (int tn = 0; tn < 4; ++tn) ru[tn] = mfma16(hA, wg[tn], unpk2(gc[tn]));
#pragma unroll
    for (int tn = 0; tn < 4; ++tn)
#pragma unroll
      for (int r = 0; r < 4; ++r) ru[tn][r] = sgm(ru[tn][r]);

#pragma unroll
    for (int r = 0; r < 4; ++r) {
      hb0[(q * 4 + r) * 40 + nl]      = f2bf(ru[0][r] * hc0[r]);
      hb0[(q * 4 + r) * 40 + 16 + nl] = f2bf(ru[1][r] * hc1[r]);
    }
    __syncthreads();
    short8 rhA = *reinterpret_cast<const short8*>(hb0 + nl * 40 + q * 8);

    f32x4 cc0 = mfma16(rhA, wc[0], unpk2(gc[4]));
    f32x4 cc1 = mfma16(rhA, wc[1], unpk2(gc[5]));
#pragma unroll
    for (int r = 0; r < 4; ++r) {
      const float c0 = tnh(cc0[r]), c1 = tnh(cc1[r]);
      const float u0 = ru[2][r], u1 = ru[3][r];
      hc0[r] = u0 * hc0[r] + (1.f - u0) * c0;
      hc1[r] = u1 * hc1[r] + (1.f - u1) * c1;
    }

#pragma unroll
    for (int r = 0; r < 4; ++r) {
      hb1[(q * 4 + r) * 40 + nl]      = f2bf(hc0[r]);
      hb1[(q * 4 + r) * 40 + 16 + nl] = f2bf(hc1[r]);
    }
    __syncthreads();
    hA = *reinterpret_cast<const short8*>(hb1 + nl * 40 + q * 8);
    y0a[((size_t)(t * 512 + btile) * 2 + dir) * 64 + lane] = __builtin_bit_cast(uint4, hA);

    if (s < 20) {
#pragma unroll
      for (int tn = 0; tn < 6; ++tn) gc[tn] = gn[tn];
    }
  }
}

// ---------------------------------------------------------------------------
// K2b: layer-1 x-projection. A = y0a frags (K=64: fw|bw), B = Wx1 rows 0..63.
// Writes gxcx1 (same format as gxcx0, bias included). No gather — MFMA-dense.
// ---------------------------------------------------------------------------
__global__ __launch_bounds__(256, 2) void k2b(
    const ushort_t* __restrict__ cvt, const uint4* __restrict__ y0a,
    uint2* __restrict__ gxcx1) {
  const int wave = (int)((blockIdx.x * blockDim.x + threadIdx.x) >> 6);
  const int lane = threadIdx.x & 63;
  const int q = lane >> 4, nl = lane & 15;
  const int dir = wave & 1;
  const int mg = wave >> 1;
  if (mg >= NMG) return;

  const ushort_t* gk = cvt + (dir ? U_GKBW1 : U_GKFW1);
  const ushort_t* ck = cvt + (dir ? U_CKBW1 : U_CKFW1);
  const ushort_t* gb = cvt + (dir ? U_GBBW1 : U_GBFW1);
  const ushort_t* cb = cvt + (dir ? U_CBBW1 : U_CBFW1);

  short8 wf[2][6];
#pragma unroll
  for (int kt = 0; kt < 2; ++kt) {
#pragma unroll
    for (int tn = 0; tn < 6; ++tn) {
      const ushort_t* src = (tn < 4) ? gk : ck;
      const int ncol = (tn < 4) ? 64 : 32;
      const int n = (tn < 4) ? tn * 16 + nl : (tn - 4) * 16 + nl;
      short8 v;
#pragma unroll
      for (int j = 0; j < 8; ++j)
        v[j] = (short)src[(kt * 32 + q * 8 + j) * ncol + n];
      wf[kt][tn] = v;
    }
  }
  float bias[6];
#pragma unroll
  for (int tn = 0; tn < 6; ++tn)
    bias[tn] = bf2f((tn < 4) ? (unsigned)gb[tn * 16 + nl]
                             : (unsigned)cb[(tn - 4) * 16 + nl]);

  for (int mi = 0; mi < 8; ++mi) {
    const int mtile = mg * 8 + mi;
    const short8 ya0 = __builtin_bit_cast(short8, y0a[((size_t)mtile * 2 + 0) * 64 + lane]);
    const short8 ya1 = __builtin_bit_cast(short8, y0a[((size_t)mtile * 2 + 1) * 64 + lane]);
#pragma unroll
    for (int tn = 0; tn < 6; ++tn) {
      f32x4 acc = {bias[tn], bias[tn], bias[tn], bias[tn]};
      acc = mfma16(ya0, wf[0][tn], acc);
      acc = mfma16(ya1, wf[1][tn], acc);
      uint2 o;
      o.x = (unsigned)f2bf(acc[0]) | ((unsigned)f2bf(acc[1]) << 16);
      o.y = (unsigned)f2bf(acc[2]) | ((unsigned)f2bf(acc[3]) << 16);
      gxcx1[(((size_t)dir * NMT + mtile) * 6 + tn) * 64 + lane] = o;
    }
  }
}

// ---------------------------------------------------------------------------
// K3b: layer-1 recurrence (6 MFMA/step). FP32 output [b][21][64].
// ---------------------------------------------------------------------------
__global__ __launch_bounds__(256) void k3b(
    const ushort_t* __restrict__ cvt, const uint2* __restrict__ gxcx1,
    float* __restrict__ out) {
  __shared__ __align__(16) ushort_t hbuf[4][2][16 * 40];
  const int wv = threadIdx.x >> 6;
  const int lane = threadIdx.x & 63;
  const int q = lane >> 4, nl = lane & 15;
  const int job = blockIdx.x * 4 + wv;
  const int dir = job & 1, btile = job >> 1;
  const ushort_t* gk = cvt + (dir ? U_GKBW1 : U_GKFW1);
  const ushort_t* ck = cvt + (dir ? U_CKBW1 : U_CKFW1);

  short8 wg[4], wc[2];
#pragma unroll
  for (int tn = 0; tn < 4; ++tn) {
    short8 v;
#pragma unroll
    for (int j = 0; j < 8; ++j) v[j] = (short)gk[(64 + q * 8 + j) * 64 + tn * 16 + nl];
    wg[tn] = v;
  }
#pragma unroll
  for (int tn = 0; tn < 2; ++tn) {
    short8 v;
#pragma unroll
    for (int j = 0; j < 8; ++j) v[j] = (short)ck[(64 + q * 8 + j) * 32 + tn * 16 + nl];
    wc[tn] = v;
  }

  f32x4 hc0 = {0.f, 0.f, 0.f, 0.f}, hc1 = {0.f, 0.f, 0.f, 0.f};
  short8 hA = {0, 0, 0, 0, 0, 0, 0, 0};
  ushort_t* hb0 = hbuf[wv][0];
  ushort_t* hb1 = hbuf[wv][1];

  const size_t dbase = (size_t)dir * NMT;
  uint2 gc[6], gn[6];
  {
    const int t0 = dir ? 20 : 0;
#pragma unroll
    for (int tn = 0; tn < 6; ++tn)
      gc[tn] = gxcx1[((dbase + (size_t)(t0 * 512 + btile)) * 6 + tn) * 64 + lane];
  }

  for (int s = 0; s < 21; ++s) {
    const int t = dir ? 20 - s : s;
    if (s < 20) {
      const int t2 = dir ? t - 1 : t + 1;
#pragma unroll
      for (int tn = 0; tn < 6; ++tn)
        gn[tn] = gxcx1[((dbase + (size_t)(t2 * 512 + btile)) * 6 + tn) * 64 + lane];
    }

    f32x4 ru[4];
#pragma unroll
    for (int tn = 0; tn < 4; ++tn) ru[tn] = mfma16(hA, wg[tn], unpk2(gc[tn]));
#pragma unroll
    for (int tn = 0; tn < 4; ++tn)
#pragma unroll
      for (int r = 0; r < 4; ++r) ru[tn][r] = sgm(ru[tn][r]);

#pragma unroll
    for (int r = 0; r < 4; ++r) {
      hb0[(q * 4 + r) * 40 + nl]      = f2bf(ru[0][r] * hc0[r]);
      hb0[(q * 4 + r) * 40 + 16 + nl] = f2bf(ru[1][r] * hc1[r]);
    }
    __syncthreads();
    short8 rhA = *reinterpret_cast<const short8*>(hb0 + nl * 40 + q * 8);

    f32x4 cc0 = mfma16(rhA, wc[0], unpk2(gc[4]));
    f32x4 cc1 = mfma16(rhA, wc[1], unpk2(gc[5]));
#pragma unroll
    for (int r = 0; r < 4; ++r) {
      const float c0 = tnh(cc0[r]), c1 = tnh(cc1[r]);
      const float u0 = ru[2][r], u1 = ru[3][r];
      hc0[r] = u0 * hc0[r] + (1.f - u0) * c0;
      hc1[r] = u1 * hc1[r] + (1.f - u1) * c1;
    }

#pragma unroll
    for (int r = 0; r < 4; ++r) {
      hb1[(q * 4 + r) * 40 + nl]      = f2bf(hc0[r]);
      hb1[(q * 4 + r) * 40 + 16 + nl] = f2bf(hc1[r]);
    }
    __syncthreads();
    hA = *reinterpret_cast<const short8*>(hb1 + nl * 40 + q * 8);

#pragma unroll
    for (int r = 0; r < 4; ++r) {
      const size_t o = ((size_t)(btile * 16 + q * 4 + r) * 21 + t) * 64 + dir * 32 + nl;
      out[o]      = hc0[r];
      out[o + 16] = hc1[r];
    }

    if (s < 20) {
#pragma unroll
      for (int tn = 0; tn < 6; ++tn) gc[tn] = gn[tn];
    }
  }
}

// ---------------------------------------------------------------------------
extern "C" void kernel_launch(void* const* d_in, const int* in_sizes, int n_in,
                              void* d_out, int out_size, void* d_ws, size_t ws_size,
                              hipStream_t stream)
{
  const int* tok_b = (const int*)d_in[0];
  const void* slot_tb = d_in[1];
  const void* slot_mb = d_in[2];
  const int* tok_a = (const int*)d_in[3];
  const void* slot_ta = d_in[4];
  const void* slot_ma = d_in[5];

  int* flags = (int*)d_ws;
  ushort_t* cvt = (ushort_t*)((char*)d_ws + 64);
  ushort_t* mbits = (ushort_t*)((char*)d_ws + MB_OFF);
  uint2* gxcx = (uint2*)((char*)d_ws + GX_OFF);
  uint4* y0a = (uint4*)((char*)d_ws + Y0A_OFF);

  k0_detect<<<dim3(1), dim3(64), 0, stream>>>(
      (const ushort_t*)d_in[6], (const unsigned*)slot_mb, (const unsigned*)slot_tb,
      flags);

  static const int slen[19] = {640000, 160000, 160,
                               12288, 64, 6144, 32, 12288, 64, 6144, 32,
                               6144, 64, 3072, 32, 6144, 64, 3072, 32};
  static const int sdst[19] = {U_TOKEMB, U_TYPEMB, U_HOLE,
                               U_GKFW0, U_GBFW0, U_CKFW0, U_CBFW0,
                               U_GKBW0, U_GBBW0, U_CKBW0, U_CBBW0,
                               U_GKFW1, U_GBFW1, U_CKFW1, U_CBFW1,
                               U_GKBW1, U_GBBW1, U_CKBW1, U_CBBW1};
  Cvt19 a;
  int tot = 0;
  for (int i = 0; i < 19; ++i) {
    a.src[i] = d_in[6 + i]; a.len[i] = slen[i]; a.dst[i] = sdst[i]; tot += slen[i];
  }
  kcvt<<<dim3((tot + 255) / 256), dim3(256), 0, stream>>>(a, cvt, flags);

  kmask<<<dim3(640), dim3(256), 0, stream>>>(
      slot_tb, slot_mb, slot_ta, slot_ma, mbits, flags);

  k2a<<<dim3(672), dim3(256), 0, stream>>>(
      tok_b, slot_tb, tok_a, slot_ta, slot_mb, slot_ma, cvt, mbits, gxcx, flags);

  k3a<<<dim3(256), dim3(256), 0, stream>>>(cvt, gxcx, y0a);

  k2b<<<dim3(672), dim3(256), 0, stream>>>(cvt, y0a, gxcx);  // aliases gxcx0

  k3b<<<dim3(256), dim3(256), 0, stream>>>(cvt, gxcx, (float*)d_out);
}